// Round 6
// baseline (438.427 us; speedup 1.0000x reference)
//
#include <hip/hip_runtime.h>

#define BN_EPS 1e-5f
#define SCAN_CHUNK 2048

// ---------------- bf16 helpers ----------------
__device__ __forceinline__ float bf2f(unsigned short u) {
  return __uint_as_float(((unsigned)u) << 16);
}
__device__ __forceinline__ unsigned short f2bf(float f) {
  unsigned b = __float_as_uint(f);
  b += 0x7FFFu + ((b >> 16) & 1u);   // round-to-nearest-even
  return (unsigned short)(b >> 16);
}

// ---------------- utility ----------------

__global__ void k_zero_int(int* __restrict__ p, int n) {
  int i = blockIdx.x * blockDim.x + threadIdx.x;
  if (i < n) p[i] = 0;
}

// ---------------- shared GEMM tile body ----------------
// Y[base+r, :] = op(X)[base+r, :K] @ W[K,64]  (op: BN+ReLU if FUSE_BN)
// epilogue: optionally scale by dinv[row]; output packed bf16.
template<int K, bool FUSE_BN, bool SCALE>
__device__ __forceinline__ void gemm_tile(float* __restrict__ Ws, float* __restrict__ Xs,
                                          float* __restrict__ bn_s, int tile,
                                          const float* __restrict__ X,
                                          const float* __restrict__ W,
                                          const float* __restrict__ dinv,
                                          const float* __restrict__ stats,
                                          const float* __restrict__ gamma,
                                          const float* __restrict__ beta,
                                          unsigned short* __restrict__ Y,
                                          int n, float inv_n) {
  constexpr int XS = K + 4;
  const int t = threadIdx.x;
  const int base = tile * 64;
  float* mean_s = bn_s;
  float* scl_s  = bn_s + 64;
  float* bt_s   = bn_s + 128;

  if (FUSE_BN) {
    if (t < 64) {
      float mean = stats[t] * inv_n;
      float var = stats[64 + t] * inv_n - mean * mean;
      mean_s[t] = mean;
      scl_s[t] = rsqrtf(var + BN_EPS) * gamma[t];
      bt_s[t] = beta[t];
    }
    __syncthreads();
  }

  {
    const float4* wv = (const float4*)W;
    float4* wsv = (float4*)Ws;
#pragma unroll
    for (int idx = t; idx < K * 16; idx += 256) wsv[idx] = wv[idx];
  }
  {
    constexpr int RV = K / 4;
    for (int idx = t; idx < 64 * RV; idx += 256) {
      int row = idx / RV, kk = idx % RV;
      float4 v = make_float4(0.f, 0.f, 0.f, 0.f);
      if (base + row < n) {
        v = *(const float4*)(X + (size_t)(base + row) * K + kk * 4);
        if (FUSE_BN) {
          int k0 = kk * 4;
          v.x = fmaxf(fmaf(v.x - mean_s[k0 + 0], scl_s[k0 + 0], bt_s[k0 + 0]), 0.f);
          v.y = fmaxf(fmaf(v.y - mean_s[k0 + 1], scl_s[k0 + 1], bt_s[k0 + 1]), 0.f);
          v.z = fmaxf(fmaf(v.z - mean_s[k0 + 2], scl_s[k0 + 2], bt_s[k0 + 2]), 0.f);
          v.w = fmaxf(fmaf(v.w - mean_s[k0 + 3], scl_s[k0 + 3], bt_s[k0 + 3]), 0.f);
        }
      }
      *(float4*)(Xs + row * XS + kk * 4) = v;
    }
  }
  __syncthreads();

  const int tc = t & 15;
  const int tr = t >> 4;

  float acc[4][4];
#pragma unroll
  for (int r = 0; r < 4; ++r)
#pragma unroll
    for (int c = 0; c < 4; ++c) acc[r][c] = 0.f;

#pragma unroll 4
  for (int k = 0; k < K; k += 4) {
    float4 xr[4], wr[4];
#pragma unroll
    for (int r = 0; r < 4; ++r) xr[r] = *(const float4*)(Xs + (tr * 4 + r) * XS + k);
#pragma unroll
    for (int kk = 0; kk < 4; ++kk) wr[kk] = *(const float4*)(Ws + (k + kk) * 64 + tc * 4);
#pragma unroll
    for (int kk = 0; kk < 4; ++kk) {
#pragma unroll
      for (int r = 0; r < 4; ++r) {
        float xv = (kk == 0) ? xr[r].x : (kk == 1) ? xr[r].y : (kk == 2) ? xr[r].z : xr[r].w;
        acc[r][0] = fmaf(xv, wr[kk].x, acc[r][0]);
        acc[r][1] = fmaf(xv, wr[kk].y, acc[r][1]);
        acc[r][2] = fmaf(xv, wr[kk].z, acc[r][2]);
        acc[r][3] = fmaf(xv, wr[kk].w, acc[r][3]);
      }
    }
  }

#pragma unroll
  for (int r = 0; r < 4; ++r) {
    int i = base + tr * 4 + r;
    if (i < n) {
      float sc = SCALE ? dinv[i] : 1.0f;
      ushort4 o;
      o.x = f2bf(acc[r][0] * sc);
      o.y = f2bf(acc[r][1] * sc);
      o.z = f2bf(acc[r][2] * sc);
      o.w = f2bf(acc[r][3] * sc);
      *(ushort4*)(Y + (size_t)i * 64 + tc * 4) = o;
    }
  }
}

// ---------------- fused: degree histogram (+rank) || GEMM1 ----------------
// Blocks [0, nbE) process 1024 edges each (deg_rank); blocks [nbE, nbE+nbT)
// compute x@W1 tiles into the UNSCALED bf16 table (dinv not yet available).
__global__ __launch_bounds__(256) void k_fused_deg_gemm1(
    const int* __restrict__ dst, int* __restrict__ cnt, int* __restrict__ rank, int E, int nbE,
    const float* __restrict__ X, const float* __restrict__ W,
    unsigned short* __restrict__ Y, int n) {
  __shared__ float Ws[128 * 64];
  __shared__ float Xs[64 * 132];
  __shared__ float bn_s[192];

  if (blockIdx.x < nbE) {
    int e0 = (blockIdx.x * 256 + threadIdx.x) * 4;
    if (e0 + 3 < E) {
      int4 d4 = *(const int4*)(dst + e0);
      int r0 = atomicAdd(&cnt[d4.x], 1);
      int r1 = atomicAdd(&cnt[d4.y], 1);
      int r2 = atomicAdd(&cnt[d4.z], 1);
      int r3 = atomicAdd(&cnt[d4.w], 1);
      *(int4*)(rank + e0) = make_int4(r0, r1, r2, r3);
    } else {
      for (int e = e0; e < E; ++e) rank[e] = atomicAdd(&cnt[dst[e]], 1);
    }
    return;
  }
  gemm_tile<128, false, false>(Ws, Xs, bn_s, blockIdx.x - nbE, X, W,
                               nullptr, nullptr, nullptr, nullptr, Y, n, 0.f);
}

// ---------------- exclusive scan (deg -> row_ptr), fused dinv ----------------

__global__ __launch_bounds__(256) void k_scan_local(const int* __restrict__ deg,
                                                    int* __restrict__ row_ptr,
                                                    int* __restrict__ blksum,
                                                    float* __restrict__ dinv, int n) {
  __shared__ int ts[256];
  int base = blockIdx.x * SCAN_CHUNK;
  int t = threadIdx.x;
  int idx0 = base + t * 8;
  int v[8];
  int s = 0;
#pragma unroll
  for (int k = 0; k < 8; ++k) {
    int i = idx0 + k;
    int d = (i < n) ? deg[i] : 0;
    if (i < n) dinv[i] = rsqrtf(1.0f + (float)d);   // self-loop included
    v[k] = s;
    s += d;
  }
  int val = s;
  ts[t] = val;
  __syncthreads();
#pragma unroll
  for (int off = 1; off < 256; off <<= 1) {
    int add = (t >= off) ? ts[t - off] : 0;
    __syncthreads();
    val += add;
    ts[t] = val;
    __syncthreads();
  }
  int excl = val - s;
#pragma unroll
  for (int k = 0; k < 8; ++k) {
    int i = idx0 + k;
    if (i < n) row_ptr[i] = excl + v[k];
  }
  if (t == 255) blksum[blockIdx.x] = val;
}

__global__ void k_scan_blk(int* __restrict__ blksum, int nblk,
                           int* __restrict__ row_ptr, int n,
                           float* __restrict__ stats) {
  for (int i = threadIdx.x; i < 128; i += 64) stats[i] = 0.f;   // fused BN-stats zero
  if (threadIdx.x == 0) {
    int run = 0;
    for (int i = 0; i < nblk; ++i) { int v = blksum[i]; blksum[i] = run; run += v; }
    row_ptr[n] = run;
  }
}

__global__ __launch_bounds__(256) void k_scan_add(int* __restrict__ row_ptr,
                                                  const int* __restrict__ blksum, int n) {
  int off = blksum[blockIdx.x];
  int base = blockIdx.x * SCAN_CHUNK;
  for (int k = threadIdx.x; k < SCAN_CHUNK; k += 256) {
    int i = base + k;
    if (i < n) row_ptr[i] += off;
  }
}

// CSR fill, atomic-free, 4 edges/thread: col[row_ptr[d] + rank[e]] = src[e]
__global__ void k_fill(const int* __restrict__ src, const int* __restrict__ dst,
                       const int* __restrict__ rank, const int* __restrict__ row_ptr,
                       int* __restrict__ col, int E) {
  int e0 = (blockIdx.x * blockDim.x + threadIdx.x) * 4;
  if (e0 + 3 < E) {
    int4 d4 = *(const int4*)(dst + e0);
    int4 r4 = *(const int4*)(rank + e0);
    int4 s4 = *(const int4*)(src + e0);
    col[row_ptr[d4.x] + r4.x] = s4.x;
    col[row_ptr[d4.y] + r4.y] = s4.y;
    col[row_ptr[d4.z] + r4.z] = s4.z;
    col[row_ptr[d4.w] + r4.w] = s4.w;
  } else {
    for (int e = e0; e < E; ++e) col[row_ptr[dst[e]] + rank[e]] = src[e];
  }
}

// ---------------- gather layer 1 (unscaled table, per-edge dinv) + BN stats ----------------
// out[i,j] = b[j] + dinv[i]*( dinv[i]*Hu[i,j] + sum_p dinv[col[p]]*Hu[col[p],j] )
__global__ __launch_bounds__(256) void k_gather1(const unsigned short* __restrict__ Hu,
                                                 const int* __restrict__ row_ptr,
                                                 const int* __restrict__ col,
                                                 const float* __restrict__ dinv,
                                                 const float* __restrict__ b,
                                                 float* __restrict__ out,
                                                 float* __restrict__ stats, int n) {
  int j = threadIdx.x & 63;
  int w = threadIdx.x >> 6;
  float bs = b[j];
  float s = 0.f, s2 = 0.f;
  for (int i = blockIdx.x * 4 + w; i < n; i += gridDim.x * 4) {
    float di = dinv[i];
    float acc = di * bf2f(Hu[(size_t)i * 64 + j]);
    int p0 = row_ptr[i], p1 = row_ptr[i + 1];
    int p = p0;
    for (; p + 4 <= p1; p += 4) {
      int c0 = col[p], c1 = col[p + 1], c2 = col[p + 2], c3 = col[p + 3];
      float d0 = dinv[c0], d1 = dinv[c1], d2 = dinv[c2], d3 = dinv[c3];
      float h0 = bf2f(Hu[(size_t)c0 * 64 + j]);
      float h1 = bf2f(Hu[(size_t)c1 * 64 + j]);
      float h2 = bf2f(Hu[(size_t)c2 * 64 + j]);
      float h3 = bf2f(Hu[(size_t)c3 * 64 + j]);
      acc = fmaf(d0, h0, acc);
      acc = fmaf(d1, h1, acc);
      acc = fmaf(d2, h2, acc);
      acc = fmaf(d3, h3, acc);
    }
    for (; p < p1; ++p) {
      int c = col[p];
      acc = fmaf(dinv[c], bf2f(Hu[(size_t)c * 64 + j]), acc);
    }
    float v = fmaf(di, acc, bs);
    out[(size_t)i * 64 + j] = v;
    s += v;
    s2 += v * v;
  }
  __shared__ float ls[256], ls2[256];
  ls[threadIdx.x] = s;
  ls2[threadIdx.x] = s2;
  __syncthreads();
  if (threadIdx.x < 64) {
    atomicAdd(&stats[j], ls[j] + ls[j + 64] + ls[j + 128] + ls[j + 192]);
    atomicAdd(&stats[64 + j], ls2[j] + ls2[j + 64] + ls2[j + 128] + ls2[j + 192]);
  }
}

// ---------------- GEMM2 standalone (BN+ReLU fused input, dinv-scaled output) ----------------
__global__ __launch_bounds__(256) void k_gemm2(const float* __restrict__ X,
                                               const float* __restrict__ W,
                                               const float* __restrict__ dinv,
                                               const float* __restrict__ stats,
                                               const float* __restrict__ gamma,
                                               const float* __restrict__ beta,
                                               unsigned short* __restrict__ Y,
                                               int n, float inv_n) {
  __shared__ float Ws[64 * 64];
  __shared__ float Xs[64 * 68];
  __shared__ float bn_s[192];
  gemm_tile<64, true, true>(Ws, Xs, bn_s, blockIdx.x, X, W, dinv, stats, gamma, beta,
                            Y, n, inv_n);
}

// ---------------- gather layer 2 (dinv-scaled table, weight-free) ----------------
__global__ __launch_bounds__(256) void k_gather2(const unsigned short* __restrict__ Hs,
                                                 const int* __restrict__ row_ptr,
                                                 const int* __restrict__ col,
                                                 const float* __restrict__ dinv,
                                                 const float* __restrict__ b,
                                                 float* __restrict__ out, int n) {
  int j = threadIdx.x & 63;
  int i = blockIdx.x * 4 + (threadIdx.x >> 6);
  if (i >= n) return;
  float acc = bf2f(Hs[(size_t)i * 64 + j]);
  int p0 = row_ptr[i], p1 = row_ptr[i + 1];
  int p = p0;
  for (; p + 8 <= p1; p += 8) {
    int s0 = col[p], s1 = col[p + 1], s2 = col[p + 2], s3 = col[p + 3];
    int s4 = col[p + 4], s5 = col[p + 5], s6 = col[p + 6], s7 = col[p + 7];
    float h0 = bf2f(Hs[(size_t)s0 * 64 + j]);
    float h1 = bf2f(Hs[(size_t)s1 * 64 + j]);
    float h2 = bf2f(Hs[(size_t)s2 * 64 + j]);
    float h3 = bf2f(Hs[(size_t)s3 * 64 + j]);
    float h4 = bf2f(Hs[(size_t)s4 * 64 + j]);
    float h5 = bf2f(Hs[(size_t)s5 * 64 + j]);
    float h6 = bf2f(Hs[(size_t)s6 * 64 + j]);
    float h7 = bf2f(Hs[(size_t)s7 * 64 + j]);
    acc += ((h0 + h1) + (h2 + h3)) + ((h4 + h5) + (h6 + h7));
  }
  for (; p < p1; ++p) acc += bf2f(Hs[(size_t)col[p] * 64 + j]);
  out[(size_t)i * 64 + j] = fmaf(dinv[i], acc, b[j]);
}

// ---------------- launch ----------------

extern "C" void kernel_launch(void* const* d_in, const int* in_sizes, int n_in,
                              void* d_out, int out_size, void* d_ws, size_t ws_size,
                              hipStream_t stream) {
  const float* x     = (const float*)d_in[0];
  const int*   ei    = (const int*)d_in[1];
  const float* W1    = (const float*)d_in[2];
  const float* b1    = (const float*)d_in[3];
  const float* W2    = (const float*)d_in[4];
  const float* b2    = (const float*)d_in[5];
  const float* gamma = (const float*)d_in[6];
  const float* beta  = (const float*)d_in[7];
  float* out = (float*)d_out;

  const int N = in_sizes[0] / 128;   // 100000
  const int E = in_sizes[1] / 2;     // 1600000
  const int* src = ei;
  const int* dst = ei + E;

  const size_t Npad = ((size_t)N + 256) & ~(size_t)255;

  // workspace layout
  char* p = (char*)d_ws;
  float* dinv    = (float*)p;               p += Npad * 4;
  int*   cnt     = (int*)p;                 p += Npad * 4;
  int*   row_ptr = (int*)p;                 p += Npad * 4;
  int*   blksum  = (int*)p;                 p += 256 * 4;
  int*   rank    = (int*)p;                 p += (size_t)E * 4;
  int*   col     = (int*)p;                 p += (size_t)E * 4;
  unsigned short* h16 = (unsigned short*)p; p += (size_t)N * 64 * 2;  // bf16 table (both layers)
  float* agg     = (float*)p;               p += (size_t)N * 64 * 4;
  float* stats   = (float*)p;               p += 128 * 4;

  int nb_n  = (N + 255) / 256;
  int nb_n4 = (N + 3) / 4;
  int nb_t  = (N + 63) / 64;
  int nbE   = (E + 1023) / 1024;    // 4 edges/thread
  int nscan = (N + SCAN_CHUNK - 1) / SCAN_CHUNK;
  float inv_n = 1.0f / (float)N;

  // ---- cnt = 0 ----
  k_zero_int<<<nb_n, 256, 0, stream>>>(cnt, N);

  // ---- fused: degree histogram + rank || GEMM1 (unscaled bf16 table) ----
  k_fused_deg_gemm1<<<nbE + nb_t, 256, 0, stream>>>(dst, cnt, rank, E, nbE,
                                                    x, W1, h16, N);

  // ---- CSR build (dinv fused into scan; stats zero fused into scan_blk) ----
  k_scan_local<<<nscan, 256, 0, stream>>>(cnt, row_ptr, blksum, dinv, N);
  k_scan_blk<<<1, 64, 0, stream>>>(blksum, nscan, row_ptr, N, stats);
  k_scan_add<<<nscan, 256, 0, stream>>>(row_ptr, blksum, N);
  k_fill<<<nbE, 256, 0, stream>>>(src, dst, rank, row_ptr, col, E);

  // ---- layer 1 aggregation + fused BN stats ----
  k_gather1<<<1024, 256, 0, stream>>>(h16, row_ptr, col, dinv, b1, agg, stats, N);

  // ---- layer 2: BN+ReLU fused GEMM -> scaled bf16 table; weight-free gather ----
  k_gemm2<<<nb_t, 256, 0, stream>>>(agg, W2, dinv, stats, gamma, beta, h16, N, inv_n);
  k_gather2<<<nb_n4, 256, 0, stream>>>(h16, row_ptr, col, dinv, b2, out, N);
}

// Round 7
// 428.632 us; speedup vs baseline: 1.0229x; 1.0229x over previous
//
#include <hip/hip_runtime.h>

#define BN_EPS 1e-5f
#define SCAN_CHUNK 2048

// ---------------- bf16 helpers ----------------
__device__ __forceinline__ float bf2f(unsigned short u) {
  return __uint_as_float(((unsigned)u) << 16);
}
__device__ __forceinline__ unsigned short f2bf(float f) {
  unsigned b = __float_as_uint(f);
  b += 0x7FFFu + ((b >> 16) & 1u);   // round-to-nearest-even
  return (unsigned short)(b >> 16);
}

// ---------------- utility ----------------

__global__ void k_zero_int(int* __restrict__ p, int n) {
  int i = blockIdx.x * blockDim.x + threadIdx.x;
  if (i < n) p[i] = 0;
}

// ---------------- shared GEMM tile body ----------------
template<int K, bool FUSE_BN, bool SCALE>
__device__ __forceinline__ void gemm_tile(float* __restrict__ Ws, float* __restrict__ Xs,
                                          float* __restrict__ bn_s, int tile,
                                          const float* __restrict__ X,
                                          const float* __restrict__ W,
                                          const float* __restrict__ dinv,
                                          const float* __restrict__ stats,
                                          const float* __restrict__ gamma,
                                          const float* __restrict__ beta,
                                          unsigned short* __restrict__ Y,
                                          int n, float inv_n) {
  constexpr int XS = K + 4;
  const int t = threadIdx.x;
  const int base = tile * 64;
  float* mean_s = bn_s;
  float* scl_s  = bn_s + 64;
  float* bt_s   = bn_s + 128;

  if (FUSE_BN) {
    if (t < 64) {
      float mean = stats[t] * inv_n;
      float var = stats[64 + t] * inv_n - mean * mean;
      mean_s[t] = mean;
      scl_s[t] = rsqrtf(var + BN_EPS) * gamma[t];
      bt_s[t] = beta[t];
    }
    __syncthreads();
  }

  {
    const float4* wv = (const float4*)W;
    float4* wsv = (float4*)Ws;
#pragma unroll
    for (int idx = t; idx < K * 16; idx += 256) wsv[idx] = wv[idx];
  }
  {
    constexpr int RV = K / 4;
    for (int idx = t; idx < 64 * RV; idx += 256) {
      int row = idx / RV, kk = idx % RV;
      float4 v = make_float4(0.f, 0.f, 0.f, 0.f);
      if (base + row < n) {
        v = *(const float4*)(X + (size_t)(base + row) * K + kk * 4);
        if (FUSE_BN) {
          int k0 = kk * 4;
          v.x = fmaxf(fmaf(v.x - mean_s[k0 + 0], scl_s[k0 + 0], bt_s[k0 + 0]), 0.f);
          v.y = fmaxf(fmaf(v.y - mean_s[k0 + 1], scl_s[k0 + 1], bt_s[k0 + 1]), 0.f);
          v.z = fmaxf(fmaf(v.z - mean_s[k0 + 2], scl_s[k0 + 2], bt_s[k0 + 2]), 0.f);
          v.w = fmaxf(fmaf(v.w - mean_s[k0 + 3], scl_s[k0 + 3], bt_s[k0 + 3]), 0.f);
        }
      }
      *(float4*)(Xs + row * XS + kk * 4) = v;
    }
  }
  __syncthreads();

  const int tc = t & 15;
  const int tr = t >> 4;

  float acc[4][4];
#pragma unroll
  for (int r = 0; r < 4; ++r)
#pragma unroll
    for (int c = 0; c < 4; ++c) acc[r][c] = 0.f;

#pragma unroll 4
  for (int k = 0; k < K; k += 4) {
    float4 xr[4], wr[4];
#pragma unroll
    for (int r = 0; r < 4; ++r) xr[r] = *(const float4*)(Xs + (tr * 4 + r) * XS + k);
#pragma unroll
    for (int kk = 0; kk < 4; ++kk) wr[kk] = *(const float4*)(Ws + (k + kk) * 64 + tc * 4);
#pragma unroll
    for (int kk = 0; kk < 4; ++kk) {
#pragma unroll
      for (int r = 0; r < 4; ++r) {
        float xv = (kk == 0) ? xr[r].x : (kk == 1) ? xr[r].y : (kk == 2) ? xr[r].z : xr[r].w;
        acc[r][0] = fmaf(xv, wr[kk].x, acc[r][0]);
        acc[r][1] = fmaf(xv, wr[kk].y, acc[r][1]);
        acc[r][2] = fmaf(xv, wr[kk].z, acc[r][2]);
        acc[r][3] = fmaf(xv, wr[kk].w, acc[r][3]);
      }
    }
  }

#pragma unroll
  for (int r = 0; r < 4; ++r) {
    int i = base + tr * 4 + r;
    if (i < n) {
      float sc = SCALE ? dinv[i] : 1.0f;
      ushort4 o;
      o.x = f2bf(acc[r][0] * sc);
      o.y = f2bf(acc[r][1] * sc);
      o.z = f2bf(acc[r][2] * sc);
      o.w = f2bf(acc[r][3] * sc);
      *(ushort4*)(Y + (size_t)i * 64 + tc * 4) = o;
    }
  }
}

// ---------------- fused: degree histogram (+rank) || GEMM1 ----------------
__global__ __launch_bounds__(256) void k_fused_deg_gemm1(
    const int* __restrict__ dst, int* __restrict__ cnt, int* __restrict__ rank, int E, int nbE,
    const float* __restrict__ X, const float* __restrict__ W,
    unsigned short* __restrict__ Y, int n) {
  __shared__ float Ws[128 * 64];
  __shared__ float Xs[64 * 132];
  __shared__ float bn_s[192];

  if (blockIdx.x < nbE) {
    int e0 = (blockIdx.x * 256 + threadIdx.x) * 4;
    if (e0 + 3 < E) {
      int4 d4 = *(const int4*)(dst + e0);
      int r0 = atomicAdd(&cnt[d4.x], 1);
      int r1 = atomicAdd(&cnt[d4.y], 1);
      int r2 = atomicAdd(&cnt[d4.z], 1);
      int r3 = atomicAdd(&cnt[d4.w], 1);
      *(int4*)(rank + e0) = make_int4(r0, r1, r2, r3);
    } else {
      for (int e = e0; e < E; ++e) rank[e] = atomicAdd(&cnt[dst[e]], 1);
    }
    return;
  }
  gemm_tile<128, false, false>(Ws, Xs, bn_s, blockIdx.x - nbE, X, W,
                               nullptr, nullptr, nullptr, nullptr, Y, n, 0.f);
}

// ---------------- exclusive scan (deg -> row_ptr), fused dinv ----------------

__global__ __launch_bounds__(256) void k_scan_local(const int* __restrict__ deg,
                                                    int* __restrict__ row_ptr,
                                                    int* __restrict__ blksum,
                                                    float* __restrict__ dinv, int n) {
  __shared__ int ts[256];
  int base = blockIdx.x * SCAN_CHUNK;
  int t = threadIdx.x;
  int idx0 = base + t * 8;
  int v[8];
  int s = 0;
#pragma unroll
  for (int k = 0; k < 8; ++k) {
    int i = idx0 + k;
    int d = (i < n) ? deg[i] : 0;
    if (i < n) dinv[i] = rsqrtf(1.0f + (float)d);   // self-loop included
    v[k] = s;
    s += d;
  }
  int val = s;
  ts[t] = val;
  __syncthreads();
#pragma unroll
  for (int off = 1; off < 256; off <<= 1) {
    int add = (t >= off) ? ts[t - off] : 0;
    __syncthreads();
    val += add;
    ts[t] = val;
    __syncthreads();
  }
  int excl = val - s;
#pragma unroll
  for (int k = 0; k < 8; ++k) {
    int i = idx0 + k;
    if (i < n) row_ptr[i] = excl + v[k];
  }
  if (t == 255) blksum[blockIdx.x] = val;
}

__global__ void k_scan_blk(int* __restrict__ blksum, int nblk,
                           int* __restrict__ row_ptr, int n,
                           float* __restrict__ stats) {
  for (int i = threadIdx.x; i < 128; i += 64) stats[i] = 0.f;   // fused BN-stats zero
  if (threadIdx.x == 0) {
    int run = 0;
    for (int i = 0; i < nblk; ++i) { int v = blksum[i]; blksum[i] = run; run += v; }
    row_ptr[n] = run;
  }
}

__global__ __launch_bounds__(256) void k_scan_add(int* __restrict__ row_ptr,
                                                  const int* __restrict__ blksum, int n) {
  int off = blksum[blockIdx.x];
  int base = blockIdx.x * SCAN_CHUNK;
  for (int k = threadIdx.x; k < SCAN_CHUNK; k += 256) {
    int i = base + k;
    if (i < n) row_ptr[i] += off;
  }
}

// ---------------- fused: CSR fill || table row-scale (h16 *= dinv[row]) ----------------
// Blocks [0, nbE): atomic-free fill, 4 edges/thread.
// Blocks [nbE, nbE+nbS): scale 2048 bf16 elements each (8/thread via uint4).
__global__ __launch_bounds__(256) void k_fused_fill_scale(
    const int* __restrict__ src, const int* __restrict__ dst,
    const int* __restrict__ rank, const int* __restrict__ row_ptr,
    int* __restrict__ col, int E, int nbE,
    unsigned short* __restrict__ h16, const float* __restrict__ dinv, int n) {
  if (blockIdx.x < nbE) {
    int e0 = (blockIdx.x * 256 + threadIdx.x) * 4;
    if (e0 + 3 < E) {
      int4 d4 = *(const int4*)(dst + e0);
      int4 r4 = *(const int4*)(rank + e0);
      int4 s4 = *(const int4*)(src + e0);
      col[row_ptr[d4.x] + r4.x] = s4.x;
      col[row_ptr[d4.y] + r4.y] = s4.y;
      col[row_ptr[d4.z] + r4.z] = s4.z;
      col[row_ptr[d4.w] + r4.w] = s4.w;
    } else {
      for (int e = e0; e < E; ++e) col[row_ptr[dst[e]] + rank[e]] = src[e];
    }
    return;
  }
  int idx = ((blockIdx.x - nbE) * 256 + threadIdx.x) * 8;   // bf16 element index
  if (idx >= n * 64) return;
  int row = idx >> 6;
  float di = dinv[row];
  uint4 v = *(const uint4*)(h16 + idx);
  unsigned r[4] = {v.x, v.y, v.z, v.w};
#pragma unroll
  for (int q = 0; q < 4; ++q) {
    float lo = bf2f((unsigned short)(r[q] & 0xFFFFu)) * di;
    float hi = bf2f((unsigned short)(r[q] >> 16)) * di;
    r[q] = ((unsigned)f2bf(hi) << 16) | f2bf(lo);
  }
  *(uint4*)(h16 + idx) = make_uint4(r[0], r[1], r[2], r[3]);
}

// ---------------- gather layer 1 (scaled table) + fused BN stats ----------------
// out[i,j] = b[j] + dinv[i]*(Hs[i,j] + sum_p Hs[col[p],j]); stats += col sums/sumsq
__global__ __launch_bounds__(256) void k_gather1(const unsigned short* __restrict__ Hs,
                                                 const int* __restrict__ row_ptr,
                                                 const int* __restrict__ col,
                                                 const float* __restrict__ dinv,
                                                 const float* __restrict__ b,
                                                 float* __restrict__ out,
                                                 float* __restrict__ stats, int n) {
  int j = threadIdx.x & 63;
  int w = threadIdx.x >> 6;
  float bs = b[j];
  float s = 0.f, s2 = 0.f;
  for (int i = blockIdx.x * 4 + w; i < n; i += gridDim.x * 4) {
    float acc = bf2f(Hs[(size_t)i * 64 + j]);
    int p0 = row_ptr[i], p1 = row_ptr[i + 1];
    int p = p0;
    for (; p + 8 <= p1; p += 8) {
      int c0 = col[p], c1 = col[p + 1], c2 = col[p + 2], c3 = col[p + 3];
      int c4 = col[p + 4], c5 = col[p + 5], c6 = col[p + 6], c7 = col[p + 7];
      float h0 = bf2f(Hs[(size_t)c0 * 64 + j]);
      float h1 = bf2f(Hs[(size_t)c1 * 64 + j]);
      float h2 = bf2f(Hs[(size_t)c2 * 64 + j]);
      float h3 = bf2f(Hs[(size_t)c3 * 64 + j]);
      float h4 = bf2f(Hs[(size_t)c4 * 64 + j]);
      float h5 = bf2f(Hs[(size_t)c5 * 64 + j]);
      float h6 = bf2f(Hs[(size_t)c6 * 64 + j]);
      float h7 = bf2f(Hs[(size_t)c7 * 64 + j]);
      acc += ((h0 + h1) + (h2 + h3)) + ((h4 + h5) + (h6 + h7));
    }
    for (; p < p1; ++p) acc += bf2f(Hs[(size_t)col[p] * 64 + j]);
    float v = fmaf(dinv[i], acc, bs);
    out[(size_t)i * 64 + j] = v;
    s += v;
    s2 += v * v;
  }
  __shared__ float ls[256], ls2[256];
  ls[threadIdx.x] = s;
  ls2[threadIdx.x] = s2;
  __syncthreads();
  if (threadIdx.x < 64) {
    atomicAdd(&stats[j], ls[j] + ls[j + 64] + ls[j + 128] + ls[j + 192]);
    atomicAdd(&stats[64 + j], ls2[j] + ls2[j + 64] + ls2[j + 128] + ls2[j + 192]);
  }
}

// ---------------- GEMM2 standalone (BN+ReLU fused input, dinv-scaled output) ----------------
__global__ __launch_bounds__(256) void k_gemm2(const float* __restrict__ X,
                                               const float* __restrict__ W,
                                               const float* __restrict__ dinv,
                                               const float* __restrict__ stats,
                                               const float* __restrict__ gamma,
                                               const float* __restrict__ beta,
                                               unsigned short* __restrict__ Y,
                                               int n, float inv_n) {
  __shared__ float Ws[64 * 64];
  __shared__ float Xs[64 * 68];
  __shared__ float bn_s[192];
  gemm_tile<64, true, true>(Ws, Xs, bn_s, blockIdx.x, X, W, dinv, stats, gamma, beta,
                            Y, n, inv_n);
}

// ---------------- gather layer 2 (scaled table, weight-free) ----------------
__global__ __launch_bounds__(256) void k_gather2(const unsigned short* __restrict__ Hs,
                                                 const int* __restrict__ row_ptr,
                                                 const int* __restrict__ col,
                                                 const float* __restrict__ dinv,
                                                 const float* __restrict__ b,
                                                 float* __restrict__ out, int n) {
  int j = threadIdx.x & 63;
  int i = blockIdx.x * 4 + (threadIdx.x >> 6);
  if (i >= n) return;
  float acc = bf2f(Hs[(size_t)i * 64 + j]);
  int p0 = row_ptr[i], p1 = row_ptr[i + 1];
  int p = p0;
  for (; p + 8 <= p1; p += 8) {
    int s0 = col[p], s1 = col[p + 1], s2 = col[p + 2], s3 = col[p + 3];
    int s4 = col[p + 4], s5 = col[p + 5], s6 = col[p + 6], s7 = col[p + 7];
    float h0 = bf2f(Hs[(size_t)s0 * 64 + j]);
    float h1 = bf2f(Hs[(size_t)s1 * 64 + j]);
    float h2 = bf2f(Hs[(size_t)s2 * 64 + j]);
    float h3 = bf2f(Hs[(size_t)s3 * 64 + j]);
    float h4 = bf2f(Hs[(size_t)s4 * 64 + j]);
    float h5 = bf2f(Hs[(size_t)s5 * 64 + j]);
    float h6 = bf2f(Hs[(size_t)s6 * 64 + j]);
    float h7 = bf2f(Hs[(size_t)s7 * 64 + j]);
    acc += ((h0 + h1) + (h2 + h3)) + ((h4 + h5) + (h6 + h7));
  }
  for (; p < p1; ++p) acc += bf2f(Hs[(size_t)col[p] * 64 + j]);
  out[(size_t)i * 64 + j] = fmaf(dinv[i], acc, b[j]);
}

// ---------------- launch ----------------

extern "C" void kernel_launch(void* const* d_in, const int* in_sizes, int n_in,
                              void* d_out, int out_size, void* d_ws, size_t ws_size,
                              hipStream_t stream) {
  const float* x     = (const float*)d_in[0];
  const int*   ei    = (const int*)d_in[1];
  const float* W1    = (const float*)d_in[2];
  const float* b1    = (const float*)d_in[3];
  const float* W2    = (const float*)d_in[4];
  const float* b2    = (const float*)d_in[5];
  const float* gamma = (const float*)d_in[6];
  const float* beta  = (const float*)d_in[7];
  float* out = (float*)d_out;

  const int N = in_sizes[0] / 128;   // 100000
  const int E = in_sizes[1] / 2;     // 1600000
  const int* src = ei;
  const int* dst = ei + E;

  const size_t Npad = ((size_t)N + 256) & ~(size_t)255;

  // workspace layout
  char* p = (char*)d_ws;
  float* dinv    = (float*)p;               p += Npad * 4;
  int*   cnt     = (int*)p;                 p += Npad * 4;
  int*   row_ptr = (int*)p;                 p += Npad * 4;
  int*   blksum  = (int*)p;                 p += 256 * 4;
  int*   rank    = (int*)p;                 p += (size_t)E * 4;
  int*   col     = (int*)p;                 p += (size_t)E * 4;
  unsigned short* h16 = (unsigned short*)p; p += (size_t)N * 64 * 2;  // bf16 table
  float* agg     = (float*)p;               p += (size_t)N * 64 * 4;
  float* stats   = (float*)p;               p += 128 * 4;

  int nb_n  = (N + 255) / 256;
  int nb_n4 = (N + 3) / 4;
  int nb_t  = (N + 63) / 64;
  int nbE   = (E + 1023) / 1024;                 // 4 edges/thread
  int nbS   = (N * 64 + 2047) / 2048;            // 8 bf16 elems/thread
  int nscan = (N + SCAN_CHUNK - 1) / SCAN_CHUNK;
  float inv_n = 1.0f / (float)N;

  // ---- cnt = 0 ----
  k_zero_int<<<nb_n, 256, 0, stream>>>(cnt, N);

  // ---- fused: degree histogram + rank || GEMM1 (unscaled bf16 table) ----
  k_fused_deg_gemm1<<<nbE + nb_t, 256, 0, stream>>>(dst, cnt, rank, E, nbE,
                                                    x, W1, h16, N);

  // ---- CSR scan (dinv fused; stats zero fused) ----
  k_scan_local<<<nscan, 256, 0, stream>>>(cnt, row_ptr, blksum, dinv, N);
  k_scan_blk<<<1, 64, 0, stream>>>(blksum, nscan, row_ptr, N, stats);
  k_scan_add<<<nscan, 256, 0, stream>>>(row_ptr, blksum, N);

  // ---- fused: CSR fill || table row-scale ----
  k_fused_fill_scale<<<nbE + nbS, 256, 0, stream>>>(src, dst, rank, row_ptr, col,
                                                    E, nbE, h16, dinv, N);

  // ---- layer 1 aggregation (full occupancy) + fused BN stats ----
  k_gather1<<<2048, 256, 0, stream>>>(h16, row_ptr, col, dinv, b1, agg, stats, N);

  // ---- layer 2: BN+ReLU fused GEMM -> scaled bf16 table; weight-free gather ----
  k_gemm2<<<nb_t, 256, 0, stream>>>(agg, W2, dinv, stats, gamma, beta, h16, N, inv_n);
  k_gather2<<<nb_n4, 256, 0, stream>>>(h16, row_ptr, col, dinv, b2, out, N);
}

// Round 8
// 409.352 us; speedup vs baseline: 1.0710x; 1.0471x over previous
//
#include <hip/hip_runtime.h>

#define BN_EPS 1e-5f
#define SCAN_CHUNK 2048

// ---------------- bf16 helpers ----------------
__device__ __forceinline__ float bf2f(unsigned short u) {
  return __uint_as_float(((unsigned)u) << 16);
}
__device__ __forceinline__ unsigned short f2bf(float f) {
  unsigned b = __float_as_uint(f);
  b += 0x7FFFu + ((b >> 16) & 1u);   // round-to-nearest-even
  return (unsigned short)(b >> 16);
}

// ---------------- utility ----------------

__global__ void k_zero_int(int* __restrict__ p, int n) {
  int i = blockIdx.x * blockDim.x + threadIdx.x;
  if (i < n) p[i] = 0;
}

// ---------------- shared GEMM tile body ----------------
template<int K, bool FUSE_BN, bool SCALE>
__device__ __forceinline__ void gemm_tile(float* __restrict__ Ws, float* __restrict__ Xs,
                                          float* __restrict__ bn_s, int tile,
                                          const float* __restrict__ X,
                                          const float* __restrict__ W,
                                          const float* __restrict__ dinv,
                                          const float* __restrict__ stats,
                                          const float* __restrict__ gamma,
                                          const float* __restrict__ beta,
                                          unsigned short* __restrict__ Y,
                                          int n, float inv_n) {
  constexpr int XS = K + 4;
  const int t = threadIdx.x;
  const int base = tile * 64;
  float* mean_s = bn_s;
  float* scl_s  = bn_s + 64;
  float* bt_s   = bn_s + 128;

  if (FUSE_BN) {
    if (t < 64) {
      float mean = stats[t] * inv_n;
      float var = stats[64 + t] * inv_n - mean * mean;
      mean_s[t] = mean;
      scl_s[t] = rsqrtf(var + BN_EPS) * gamma[t];
      bt_s[t] = beta[t];
    }
    __syncthreads();
  }

  {
    const float4* wv = (const float4*)W;
    float4* wsv = (float4*)Ws;
#pragma unroll
    for (int idx = t; idx < K * 16; idx += 256) wsv[idx] = wv[idx];
  }
  {
    constexpr int RV = K / 4;
    for (int idx = t; idx < 64 * RV; idx += 256) {
      int row = idx / RV, kk = idx % RV;
      float4 v = make_float4(0.f, 0.f, 0.f, 0.f);
      if (base + row < n) {
        v = *(const float4*)(X + (size_t)(base + row) * K + kk * 4);
        if (FUSE_BN) {
          int k0 = kk * 4;
          v.x = fmaxf(fmaf(v.x - mean_s[k0 + 0], scl_s[k0 + 0], bt_s[k0 + 0]), 0.f);
          v.y = fmaxf(fmaf(v.y - mean_s[k0 + 1], scl_s[k0 + 1], bt_s[k0 + 1]), 0.f);
          v.z = fmaxf(fmaf(v.z - mean_s[k0 + 2], scl_s[k0 + 2], bt_s[k0 + 2]), 0.f);
          v.w = fmaxf(fmaf(v.w - mean_s[k0 + 3], scl_s[k0 + 3], bt_s[k0 + 3]), 0.f);
        }
      }
      *(float4*)(Xs + row * XS + kk * 4) = v;
    }
  }
  __syncthreads();

  const int tc = t & 15;
  const int tr = t >> 4;

  float acc[4][4];
#pragma unroll
  for (int r = 0; r < 4; ++r)
#pragma unroll
    for (int c = 0; c < 4; ++c) acc[r][c] = 0.f;

#pragma unroll 4
  for (int k = 0; k < K; k += 4) {
    float4 xr[4], wr[4];
#pragma unroll
    for (int r = 0; r < 4; ++r) xr[r] = *(const float4*)(Xs + (tr * 4 + r) * XS + k);
#pragma unroll
    for (int kk = 0; kk < 4; ++kk) wr[kk] = *(const float4*)(Ws + (k + kk) * 64 + tc * 4);
#pragma unroll
    for (int kk = 0; kk < 4; ++kk) {
#pragma unroll
      for (int r = 0; r < 4; ++r) {
        float xv = (kk == 0) ? xr[r].x : (kk == 1) ? xr[r].y : (kk == 2) ? xr[r].z : xr[r].w;
        acc[r][0] = fmaf(xv, wr[kk].x, acc[r][0]);
        acc[r][1] = fmaf(xv, wr[kk].y, acc[r][1]);
        acc[r][2] = fmaf(xv, wr[kk].z, acc[r][2]);
        acc[r][3] = fmaf(xv, wr[kk].w, acc[r][3]);
      }
    }
  }

#pragma unroll
  for (int r = 0; r < 4; ++r) {
    int i = base + tr * 4 + r;
    if (i < n) {
      float sc = SCALE ? dinv[i] : 1.0f;
      ushort4 o;
      o.x = f2bf(acc[r][0] * sc);
      o.y = f2bf(acc[r][1] * sc);
      o.z = f2bf(acc[r][2] * sc);
      o.w = f2bf(acc[r][3] * sc);
      *(ushort4*)(Y + (size_t)i * 64 + tc * 4) = o;
    }
  }
}

// ---------------- fused: degree histogram (+rank) || GEMM1, parity-interleaved ----------------
// Even blocks (within paired range) do edge atomics; odd blocks do GEMM tiles.
// This keeps both roles co-resident for the whole kernel so the GEMM hides
// under the atomic-bound phase (R7: consecutive role ranges ran serially).
__global__ __launch_bounds__(256) void k_fused_deg_gemm1(
    const int* __restrict__ dst, int* __restrict__ cnt, int* __restrict__ rank, int E, int nbE,
    const float* __restrict__ X, const float* __restrict__ W,
    unsigned short* __restrict__ Y, int n, int nbT) {
  __shared__ float Ws[128 * 64];
  __shared__ float Xs[64 * 132];
  __shared__ float bn_s[192];

  int paired = 2 * (nbE < nbT ? nbE : nbT);
  int role, idx;
  if ((int)blockIdx.x < paired) {
    role = blockIdx.x & 1;
    idx = blockIdx.x >> 1;
  } else {
    int r = blockIdx.x - paired;
    if (nbE > nbT) { role = 0; idx = nbT + r; }
    else           { role = 1; idx = nbE + r; }
  }

  if (role == 0) {
    int e0 = (idx * 256 + threadIdx.x) * 4;
    if (e0 + 3 < E) {
      int4 d4 = *(const int4*)(dst + e0);
      int r0 = atomicAdd(&cnt[d4.x], 1);
      int r1 = atomicAdd(&cnt[d4.y], 1);
      int r2 = atomicAdd(&cnt[d4.z], 1);
      int r3 = atomicAdd(&cnt[d4.w], 1);
      *(int4*)(rank + e0) = make_int4(r0, r1, r2, r3);
    } else {
      for (int e = e0; e < E; ++e) rank[e] = atomicAdd(&cnt[dst[e]], 1);
    }
    return;
  }
  gemm_tile<128, false, false>(Ws, Xs, bn_s, idx, X, W,
                               nullptr, nullptr, nullptr, nullptr, Y, n, 0.f);
}

// ---------------- exclusive scan (deg -> row_ptr), fused dinv ----------------

__global__ __launch_bounds__(256) void k_scan_local(const int* __restrict__ deg,
                                                    int* __restrict__ row_ptr,
                                                    int* __restrict__ blksum,
                                                    float* __restrict__ dinv, int n) {
  __shared__ int ts[256];
  int base = blockIdx.x * SCAN_CHUNK;
  int t = threadIdx.x;
  int idx0 = base + t * 8;
  int v[8];
  int s = 0;
#pragma unroll
  for (int k = 0; k < 8; ++k) {
    int i = idx0 + k;
    int d = (i < n) ? deg[i] : 0;
    if (i < n) dinv[i] = rsqrtf(1.0f + (float)d);   // self-loop included
    v[k] = s;
    s += d;
  }
  int val = s;
  ts[t] = val;
  __syncthreads();
#pragma unroll
  for (int off = 1; off < 256; off <<= 1) {
    int add = (t >= off) ? ts[t - off] : 0;
    __syncthreads();
    val += add;
    ts[t] = val;
    __syncthreads();
  }
  int excl = val - s;
#pragma unroll
  for (int k = 0; k < 8; ++k) {
    int i = idx0 + k;
    if (i < n) row_ptr[i] = excl + v[k];
  }
  if (t == 255) blksum[blockIdx.x] = val;
}

__global__ void k_scan_blk(int* __restrict__ blksum, int nblk,
                           int* __restrict__ row_ptr, int n,
                           float* __restrict__ stats) {
  for (int i = threadIdx.x; i < 128; i += 64) stats[i] = 0.f;   // fused BN-stats zero
  if (threadIdx.x == 0) {
    int run = 0;
    for (int i = 0; i < nblk; ++i) { int v = blksum[i]; blksum[i] = run; run += v; }
    row_ptr[n] = run;
  }
}

__global__ __launch_bounds__(256) void k_scan_add(int* __restrict__ row_ptr,
                                                  const int* __restrict__ blksum, int n) {
  int off = blksum[blockIdx.x];
  int base = blockIdx.x * SCAN_CHUNK;
  for (int k = threadIdx.x; k < SCAN_CHUNK; k += 256) {
    int i = base + k;
    if (i < n) row_ptr[i] += off;
  }
}

// ---------------- fused: CSR fill || table row-scale, mod-3 interleaved ----------------
// u%3==0 -> fill block (idx u/3); else scale block (idx u - u/3 - 1).
// fill:scale block ratio is ~1:2, matching their counts (nbE vs ~2*nbE).
__global__ __launch_bounds__(256) void k_fused_fill_scale(
    const int* __restrict__ src, const int* __restrict__ dst,
    const int* __restrict__ rank, const int* __restrict__ row_ptr,
    int* __restrict__ col, int E, int nbE,
    unsigned short* __restrict__ h16, const float* __restrict__ dinv, int n) {
  int u = blockIdx.x;
  int fi = u / 3;
  bool is_fill = (u % 3 == 0) && (fi < nbE);
  if (!is_fill && (u % 3 == 0)) return;   // overflow fill stripe (shouldn't happen)
  if (is_fill) {
    int e0 = (fi * 256 + threadIdx.x) * 4;
    if (e0 + 3 < E) {
      int4 d4 = *(const int4*)(dst + e0);
      int4 r4 = *(const int4*)(rank + e0);
      int4 s4 = *(const int4*)(src + e0);
      col[row_ptr[d4.x] + r4.x] = s4.x;
      col[row_ptr[d4.y] + r4.y] = s4.y;
      col[row_ptr[d4.z] + r4.z] = s4.z;
      col[row_ptr[d4.w] + r4.w] = s4.w;
    } else {
      for (int e = e0; e < E; ++e) col[row_ptr[dst[e]] + rank[e]] = src[e];
    }
    return;
  }
  int si = u - fi - 1;                     // scale block index
  int idx = (si * 256 + threadIdx.x) * 8;  // bf16 element index
  if (idx >= n * 64) return;
  int row = idx >> 6;
  float di = dinv[row];
  uint4 v = *(const uint4*)(h16 + idx);
  unsigned r[4] = {v.x, v.y, v.z, v.w};
#pragma unroll
  for (int q = 0; q < 4; ++q) {
    float lo = bf2f((unsigned short)(r[q] & 0xFFFFu)) * di;
    float hi = bf2f((unsigned short)(r[q] >> 16)) * di;
    r[q] = ((unsigned)f2bf(hi) << 16) | f2bf(lo);
  }
  *(uint4*)(h16 + idx) = make_uint4(r[0], r[1], r[2], r[3]);
}

// ---------------- gather layer 1 (scaled table) + fused BN stats ----------------
__global__ __launch_bounds__(256) void k_gather1(const unsigned short* __restrict__ Hs,
                                                 const int* __restrict__ row_ptr,
                                                 const int* __restrict__ col,
                                                 const float* __restrict__ dinv,
                                                 const float* __restrict__ b,
                                                 float* __restrict__ out,
                                                 float* __restrict__ stats, int n) {
  int j = threadIdx.x & 63;
  int w = threadIdx.x >> 6;
  float bs = b[j];
  float s = 0.f, s2 = 0.f;
  for (int i = blockIdx.x * 4 + w; i < n; i += gridDim.x * 4) {
    float acc = bf2f(Hs[(size_t)i * 64 + j]);
    int p0 = row_ptr[i], p1 = row_ptr[i + 1];
    int p = p0;
    for (; p + 8 <= p1; p += 8) {
      int c0 = col[p], c1 = col[p + 1], c2 = col[p + 2], c3 = col[p + 3];
      int c4 = col[p + 4], c5 = col[p + 5], c6 = col[p + 6], c7 = col[p + 7];
      float h0 = bf2f(Hs[(size_t)c0 * 64 + j]);
      float h1 = bf2f(Hs[(size_t)c1 * 64 + j]);
      float h2 = bf2f(Hs[(size_t)c2 * 64 + j]);
      float h3 = bf2f(Hs[(size_t)c3 * 64 + j]);
      float h4 = bf2f(Hs[(size_t)c4 * 64 + j]);
      float h5 = bf2f(Hs[(size_t)c5 * 64 + j]);
      float h6 = bf2f(Hs[(size_t)c6 * 64 + j]);
      float h7 = bf2f(Hs[(size_t)c7 * 64 + j]);
      acc += ((h0 + h1) + (h2 + h3)) + ((h4 + h5) + (h6 + h7));
    }
    for (; p < p1; ++p) acc += bf2f(Hs[(size_t)col[p] * 64 + j]);
    float v = fmaf(dinv[i], acc, bs);
    out[(size_t)i * 64 + j] = v;
    s += v;
    s2 += v * v;
  }
  __shared__ float ls[256], ls2[256];
  ls[threadIdx.x] = s;
  ls2[threadIdx.x] = s2;
  __syncthreads();
  if (threadIdx.x < 64) {
    atomicAdd(&stats[j], ls[j] + ls[j + 64] + ls[j + 128] + ls[j + 192]);
    atomicAdd(&stats[64 + j], ls2[j] + ls2[j + 64] + ls2[j + 128] + ls2[j + 192]);
  }
}

// ---------------- GEMM2 standalone (BN+ReLU fused input, dinv-scaled output) ----------------
__global__ __launch_bounds__(256) void k_gemm2(const float* __restrict__ X,
                                               const float* __restrict__ W,
                                               const float* __restrict__ dinv,
                                               const float* __restrict__ stats,
                                               const float* __restrict__ gamma,
                                               const float* __restrict__ beta,
                                               unsigned short* __restrict__ Y,
                                               int n, float inv_n) {
  __shared__ float Ws[64 * 64];
  __shared__ float Xs[64 * 68];
  __shared__ float bn_s[192];
  gemm_tile<64, true, true>(Ws, Xs, bn_s, blockIdx.x, X, W, dinv, stats, gamma, beta,
                            Y, n, inv_n);
}

// ---------------- gather layer 2 (scaled table, weight-free) ----------------
__global__ __launch_bounds__(256) void k_gather2(const unsigned short* __restrict__ Hs,
                                                 const int* __restrict__ row_ptr,
                                                 const int* __restrict__ col,
                                                 const float* __restrict__ dinv,
                                                 const float* __restrict__ b,
                                                 float* __restrict__ out, int n) {
  int j = threadIdx.x & 63;
  int i = blockIdx.x * 4 + (threadIdx.x >> 6);
  if (i >= n) return;
  float acc = bf2f(Hs[(size_t)i * 64 + j]);
  int p0 = row_ptr[i], p1 = row_ptr[i + 1];
  int p = p0;
  for (; p + 8 <= p1; p += 8) {
    int s0 = col[p], s1 = col[p + 1], s2 = col[p + 2], s3 = col[p + 3];
    int s4 = col[p + 4], s5 = col[p + 5], s6 = col[p + 6], s7 = col[p + 7];
    float h0 = bf2f(Hs[(size_t)s0 * 64 + j]);
    float h1 = bf2f(Hs[(size_t)s1 * 64 + j]);
    float h2 = bf2f(Hs[(size_t)s2 * 64 + j]);
    float h3 = bf2f(Hs[(size_t)s3 * 64 + j]);
    float h4 = bf2f(Hs[(size_t)s4 * 64 + j]);
    float h5 = bf2f(Hs[(size_t)s5 * 64 + j]);
    float h6 = bf2f(Hs[(size_t)s6 * 64 + j]);
    float h7 = bf2f(Hs[(size_t)s7 * 64 + j]);
    acc += ((h0 + h1) + (h2 + h3)) + ((h4 + h5) + (h6 + h7));
  }
  for (; p < p1; ++p) acc += bf2f(Hs[(size_t)col[p] * 64 + j]);
  out[(size_t)i * 64 + j] = fmaf(dinv[i], acc, b[j]);
}

// ---------------- launch ----------------

extern "C" void kernel_launch(void* const* d_in, const int* in_sizes, int n_in,
                              void* d_out, int out_size, void* d_ws, size_t ws_size,
                              hipStream_t stream) {
  const float* x     = (const float*)d_in[0];
  const int*   ei    = (const int*)d_in[1];
  const float* W1    = (const float*)d_in[2];
  const float* b1    = (const float*)d_in[3];
  const float* W2    = (const float*)d_in[4];
  const float* b2    = (const float*)d_in[5];
  const float* gamma = (const float*)d_in[6];
  const float* beta  = (const float*)d_in[7];
  float* out = (float*)d_out;

  const int N = in_sizes[0] / 128;   // 100000
  const int E = in_sizes[1] / 2;     // 1600000
  const int* src = ei;
  const int* dst = ei + E;

  const size_t Npad = ((size_t)N + 256) & ~(size_t)255;

  // workspace layout
  char* p = (char*)d_ws;
  float* dinv    = (float*)p;               p += Npad * 4;
  int*   cnt     = (int*)p;                 p += Npad * 4;
  int*   row_ptr = (int*)p;                 p += Npad * 4;
  int*   blksum  = (int*)p;                 p += 256 * 4;
  int*   rank    = (int*)p;                 p += (size_t)E * 4;
  int*   col     = (int*)p;                 p += (size_t)E * 4;
  unsigned short* h16 = (unsigned short*)p; p += (size_t)N * 64 * 2;  // bf16 table
  float* agg     = (float*)p;               p += (size_t)N * 64 * 4;
  float* stats   = (float*)p;               p += 128 * 4;

  int nb_n  = (N + 255) / 256;
  int nb_n4 = (N + 3) / 4;
  int nb_t  = (N + 63) / 64;
  int nbE   = (E + 1023) / 1024;                 // 4 edges/thread
  int nbS   = (N * 64 + 2047) / 2048;            // 8 bf16 elems/thread
  int nscan = (N + SCAN_CHUNK - 1) / SCAN_CHUNK;
  float inv_n = 1.0f / (float)N;

  // ---- cnt = 0 ----
  k_zero_int<<<nb_n, 256, 0, stream>>>(cnt, N);

  // ---- fused: degree histogram + rank || GEMM1, parity-interleaved ----
  k_fused_deg_gemm1<<<nbE + nb_t, 256, 0, stream>>>(dst, cnt, rank, E, nbE,
                                                    x, W1, h16, N, nb_t);

  // ---- CSR scan (dinv fused; stats zero fused) ----
  k_scan_local<<<nscan, 256, 0, stream>>>(cnt, row_ptr, blksum, dinv, N);
  k_scan_blk<<<1, 64, 0, stream>>>(blksum, nscan, row_ptr, N, stats);
  k_scan_add<<<nscan, 256, 0, stream>>>(row_ptr, blksum, N);

  // ---- fused: CSR fill || table row-scale, mod-3 interleaved ----
  k_fused_fill_scale<<<nbE + nbS, 256, 0, stream>>>(src, dst, rank, row_ptr, col,
                                                    E, nbE, h16, dinv, N);

  // ---- layer 1 aggregation (full occupancy) + fused BN stats ----
  k_gather1<<<2048, 256, 0, stream>>>(h16, row_ptr, col, dinv, b1, agg, stats, N);

  // ---- layer 2: BN+ReLU fused GEMM -> scaled bf16 table; weight-free gather ----
  k_gemm2<<<nb_t, 256, 0, stream>>>(agg, W2, dinv, stats, gamma, beta, h16, N, inv_n);
  k_gather2<<<nb_n4, 256, 0, stream>>>(h16, row_ptr, col, dinv, b2, out, N);
}

// Round 9
// 402.883 us; speedup vs baseline: 1.0882x; 1.0161x over previous
//
#include <hip/hip_runtime.h>

#define BN_EPS 1e-5f
#define SCAN_CHUNK 2048

// ---------------- bf16 helpers ----------------
__device__ __forceinline__ float bf2f(unsigned short u) {
  return __uint_as_float(((unsigned)u) << 16);
}
__device__ __forceinline__ unsigned short f2bf(float f) {
  unsigned b = __float_as_uint(f);
  b += 0x7FFFu + ((b >> 16) & 1u);   // round-to-nearest-even
  return (unsigned short)(b >> 16);
}

// ---------------- utility ----------------

__global__ void k_zero_int(int* __restrict__ p, int n) {
  int i = blockIdx.x * blockDim.x + threadIdx.x;
  if (i < n) p[i] = 0;
}

// ---------------- shared GEMM tile body ----------------
template<int K, bool FUSE_BN, bool SCALE>
__device__ __forceinline__ void gemm_tile(float* __restrict__ Ws, float* __restrict__ Xs,
                                          float* __restrict__ bn_s, int tile,
                                          const float* __restrict__ X,
                                          const float* __restrict__ W,
                                          const float* __restrict__ dinv,
                                          const float* __restrict__ stats,
                                          const float* __restrict__ gamma,
                                          const float* __restrict__ beta,
                                          unsigned short* __restrict__ Y,
                                          int n, float inv_n) {
  constexpr int XS = K + 4;
  const int t = threadIdx.x;
  const int base = tile * 64;
  float* mean_s = bn_s;
  float* scl_s  = bn_s + 64;
  float* bt_s   = bn_s + 128;

  if (FUSE_BN) {
    if (t < 64) {
      float mean = stats[t] * inv_n;
      float var = stats[64 + t] * inv_n - mean * mean;
      mean_s[t] = mean;
      scl_s[t] = rsqrtf(var + BN_EPS) * gamma[t];
      bt_s[t] = beta[t];
    }
    __syncthreads();
  }

  {
    const float4* wv = (const float4*)W;
    float4* wsv = (float4*)Ws;
#pragma unroll
    for (int idx = t; idx < K * 16; idx += 256) wsv[idx] = wv[idx];
  }
  {
    constexpr int RV = K / 4;
    for (int idx = t; idx < 64 * RV; idx += 256) {
      int row = idx / RV, kk = idx % RV;
      float4 v = make_float4(0.f, 0.f, 0.f, 0.f);
      if (base + row < n) {
        v = *(const float4*)(X + (size_t)(base + row) * K + kk * 4);
        if (FUSE_BN) {
          int k0 = kk * 4;
          v.x = fmaxf(fmaf(v.x - mean_s[k0 + 0], scl_s[k0 + 0], bt_s[k0 + 0]), 0.f);
          v.y = fmaxf(fmaf(v.y - mean_s[k0 + 1], scl_s[k0 + 1], bt_s[k0 + 1]), 0.f);
          v.z = fmaxf(fmaf(v.z - mean_s[k0 + 2], scl_s[k0 + 2], bt_s[k0 + 2]), 0.f);
          v.w = fmaxf(fmaf(v.w - mean_s[k0 + 3], scl_s[k0 + 3], bt_s[k0 + 3]), 0.f);
        }
      }
      *(float4*)(Xs + row * XS + kk * 4) = v;
    }
  }
  __syncthreads();

  const int tc = t & 15;
  const int tr = t >> 4;

  float acc[4][4];
#pragma unroll
  for (int r = 0; r < 4; ++r)
#pragma unroll
    for (int c = 0; c < 4; ++c) acc[r][c] = 0.f;

#pragma unroll 4
  for (int k = 0; k < K; k += 4) {
    float4 xr[4], wr[4];
#pragma unroll
    for (int r = 0; r < 4; ++r) xr[r] = *(const float4*)(Xs + (tr * 4 + r) * XS + k);
#pragma unroll
    for (int kk = 0; kk < 4; ++kk) wr[kk] = *(const float4*)(Ws + (k + kk) * 64 + tc * 4);
#pragma unroll
    for (int kk = 0; kk < 4; ++kk) {
#pragma unroll
      for (int r = 0; r < 4; ++r) {
        float xv = (kk == 0) ? xr[r].x : (kk == 1) ? xr[r].y : (kk == 2) ? xr[r].z : xr[r].w;
        acc[r][0] = fmaf(xv, wr[kk].x, acc[r][0]);
        acc[r][1] = fmaf(xv, wr[kk].y, acc[r][1]);
        acc[r][2] = fmaf(xv, wr[kk].z, acc[r][2]);
        acc[r][3] = fmaf(xv, wr[kk].w, acc[r][3]);
      }
    }
  }

#pragma unroll
  for (int r = 0; r < 4; ++r) {
    int i = base + tr * 4 + r;
    if (i < n) {
      float sc = SCALE ? dinv[i] : 1.0f;
      ushort4 o;
      o.x = f2bf(acc[r][0] * sc);
      o.y = f2bf(acc[r][1] * sc);
      o.z = f2bf(acc[r][2] * sc);
      o.w = f2bf(acc[r][3] * sc);
      *(ushort4*)(Y + (size_t)i * 64 + tc * 4) = o;
    }
  }
}

// ---------------- fused: degree histogram (+rank) || GEMM1, parity-interleaved ----------------
__global__ __launch_bounds__(256) void k_fused_deg_gemm1(
    const int* __restrict__ dst, int* __restrict__ cnt, int* __restrict__ rank, int E, int nbE,
    const float* __restrict__ X, const float* __restrict__ W,
    unsigned short* __restrict__ Y, int n, int nbT) {
  __shared__ float Ws[128 * 64];
  __shared__ float Xs[64 * 132];
  __shared__ float bn_s[192];

  int paired = 2 * (nbE < nbT ? nbE : nbT);
  int role, idx;
  if ((int)blockIdx.x < paired) {
    role = blockIdx.x & 1;
    idx = blockIdx.x >> 1;
  } else {
    int r = blockIdx.x - paired;
    if (nbE > nbT) { role = 0; idx = nbT + r; }
    else           { role = 1; idx = nbE + r; }
  }

  if (role == 0) {
    int e0 = (idx * 256 + threadIdx.x) * 4;
    if (e0 + 3 < E) {
      int4 d4 = *(const int4*)(dst + e0);
      int r0 = atomicAdd(&cnt[d4.x], 1);
      int r1 = atomicAdd(&cnt[d4.y], 1);
      int r2 = atomicAdd(&cnt[d4.z], 1);
      int r3 = atomicAdd(&cnt[d4.w], 1);
      *(int4*)(rank + e0) = make_int4(r0, r1, r2, r3);
    } else {
      for (int e = e0; e < E; ++e) rank[e] = atomicAdd(&cnt[dst[e]], 1);
    }
    return;
  }
  gemm_tile<128, false, false>(Ws, Xs, bn_s, idx, X, W,
                               nullptr, nullptr, nullptr, nullptr, Y, n, 0.f);
}

// ---------------- exclusive scan (deg -> row_ptr), fused dinv ----------------

__global__ __launch_bounds__(256) void k_scan_local(const int* __restrict__ deg,
                                                    int* __restrict__ row_ptr,
                                                    int* __restrict__ blksum,
                                                    float* __restrict__ dinv, int n) {
  __shared__ int ts[256];
  int base = blockIdx.x * SCAN_CHUNK;
  int t = threadIdx.x;
  int idx0 = base + t * 8;
  int v[8];
  int s = 0;
#pragma unroll
  for (int k = 0; k < 8; ++k) {
    int i = idx0 + k;
    int d = (i < n) ? deg[i] : 0;
    if (i < n) dinv[i] = rsqrtf(1.0f + (float)d);   // self-loop included
    v[k] = s;
    s += d;
  }
  int val = s;
  ts[t] = val;
  __syncthreads();
#pragma unroll
  for (int off = 1; off < 256; off <<= 1) {
    int add = (t >= off) ? ts[t - off] : 0;
    __syncthreads();
    val += add;
    ts[t] = val;
    __syncthreads();
  }
  int excl = val - s;
#pragma unroll
  for (int k = 0; k < 8; ++k) {
    int i = idx0 + k;
    if (i < n) row_ptr[i] = excl + v[k];
  }
  if (t == 255) blksum[blockIdx.x] = val;
}

__global__ void k_scan_blk(int* __restrict__ blksum, int nblk,
                           int* __restrict__ row_ptr, int n,
                           float* __restrict__ stats) {
  for (int i = threadIdx.x; i < 128; i += 64) stats[i] = 0.f;   // fused BN-stats zero
  if (threadIdx.x == 0) {
    int run = 0;
    for (int i = 0; i < nblk; ++i) { int v = blksum[i]; blksum[i] = run; run += v; }
    row_ptr[n] = run;
  }
}

__global__ __launch_bounds__(256) void k_scan_add(int* __restrict__ row_ptr,
                                                  const int* __restrict__ blksum, int n) {
  int off = blksum[blockIdx.x];
  int base = blockIdx.x * SCAN_CHUNK;
  for (int k = threadIdx.x; k < SCAN_CHUNK; k += 256) {
    int i = base + k;
    if (i < n) row_ptr[i] += off;
  }
}

// ---------------- fused: CSR fill || table row-scale, mod-3 interleaved ----------------
__global__ __launch_bounds__(256) void k_fused_fill_scale(
    const int* __restrict__ src, const int* __restrict__ dst,
    const int* __restrict__ rank, const int* __restrict__ row_ptr,
    int* __restrict__ col, int E, int nbE,
    unsigned short* __restrict__ h16, const float* __restrict__ dinv, int n) {
  int u = blockIdx.x;
  int fi = u / 3;
  bool is_fill = (u % 3 == 0) && (fi < nbE);
  if (!is_fill && (u % 3 == 0)) return;
  if (is_fill) {
    int e0 = (fi * 256 + threadIdx.x) * 4;
    if (e0 + 3 < E) {
      int4 d4 = *(const int4*)(dst + e0);
      int4 r4 = *(const int4*)(rank + e0);
      int4 s4 = *(const int4*)(src + e0);
      col[row_ptr[d4.x] + r4.x] = s4.x;
      col[row_ptr[d4.y] + r4.y] = s4.y;
      col[row_ptr[d4.z] + r4.z] = s4.z;
      col[row_ptr[d4.w] + r4.w] = s4.w;
    } else {
      for (int e = e0; e < E; ++e) col[row_ptr[dst[e]] + rank[e]] = src[e];
    }
    return;
  }
  int si = u - fi - 1;
  int idx = (si * 256 + threadIdx.x) * 8;
  if (idx >= n * 64) return;
  int row = idx >> 6;
  float di = dinv[row];
  uint4 v = *(const uint4*)(h16 + idx);
  unsigned r[4] = {v.x, v.y, v.z, v.w};
#pragma unroll
  for (int q = 0; q < 4; ++q) {
    float lo = bf2f((unsigned short)(r[q] & 0xFFFFu)) * di;
    float hi = bf2f((unsigned short)(r[q] >> 16)) * di;
    r[q] = ((unsigned)f2bf(hi) << 16) | f2bf(lo);
  }
  *(uint4*)(h16 + idx) = make_uint4(r[0], r[1], r[2], r[3]);
}

// ---------------- pair-gather: one row per wave, TWO neighbor rows per load slot ----
// Row = 64 bf16 = 32 uints. Lane l: half = l>>5 picks virtual-list index parity,
// q = l&31 picks the uint (features 2q, 2q+1). Virtual list = [self, neighbors].
// Each wave vmem instruction fetches 2 random 128B rows (one per half).
// out[i,j] = b[j] + dinv[i] * sum_list Hs[c, j]
__global__ __launch_bounds__(256) void k_gather_pair(
    const unsigned short* __restrict__ Hs,
    const int* __restrict__ row_ptr,
    const int* __restrict__ col,
    const float* __restrict__ dinv,
    const float* __restrict__ b,
    float* __restrict__ out, int n) {
  const unsigned* H32 = (const unsigned*)Hs;
  int lane = threadIdx.x & 63;
  int wv = threadIdx.x >> 6;
  int i = blockIdx.x * 4 + wv;
  if (i >= n) return;
  int half = lane >> 5;
  int q = lane & 31;
  int p0 = row_ptr[i], p1 = row_ptr[i + 1];
  int L = (p1 - p0) + 1;          // self + neighbors
  float a0 = 0.f, a1 = 0.f;
  int k = half;
  // unroll 4: 8 independent row fetches in flight per wave iteration
  for (; k + 6 < L; k += 8) {
    int c0 = (k == 0) ? i : col[p0 + k - 1];
    int c1 = col[p0 + k + 1];
    int c2 = col[p0 + k + 3];
    int c3 = col[p0 + k + 5];
    unsigned w0 = H32[(size_t)c0 * 32 + q];
    unsigned w1 = H32[(size_t)c1 * 32 + q];
    unsigned w2 = H32[(size_t)c2 * 32 + q];
    unsigned w3 = H32[(size_t)c3 * 32 + q];
    a0 += bf2f((unsigned short)(w0 & 0xFFFFu)) + bf2f((unsigned short)(w1 & 0xFFFFu))
        + bf2f((unsigned short)(w2 & 0xFFFFu)) + bf2f((unsigned short)(w3 & 0xFFFFu));
    a1 += bf2f((unsigned short)(w0 >> 16)) + bf2f((unsigned short)(w1 >> 16))
        + bf2f((unsigned short)(w2 >> 16)) + bf2f((unsigned short)(w3 >> 16));
  }
  for (; k < L; k += 2) {
    int c = (k == 0) ? i : col[p0 + k - 1];
    unsigned w = H32[(size_t)c * 32 + q];
    a0 += bf2f((unsigned short)(w & 0xFFFFu));
    a1 += bf2f((unsigned short)(w >> 16));
  }
  // combine the two halves (lane l += lane l+32)
  a0 += __shfl_down(a0, 32);
  a1 += __shfl_down(a1, 32);
  if (lane < 32) {
    float di = dinv[i];
    float2 bb = *(const float2*)(b + 2 * q);
    float2 o;
    o.x = fmaf(di, a0, bb.x);
    o.y = fmaf(di, a1, bb.y);
    *(float2*)(out + (size_t)i * 64 + 2 * q) = o;
  }
}

// ---------------- BatchNorm stats (separate pass) ----------------
__global__ __launch_bounds__(256) void k_bnstats(const float* __restrict__ A,
                                                 float* __restrict__ stats, int n) {
  int j = threadIdx.x & 63;
  int r = threadIdx.x >> 6;
  float s = 0.f, s2 = 0.f;
  for (int i = blockIdx.x * 4 + r; i < n; i += gridDim.x * 4) {
    float v = A[(size_t)i * 64 + j];
    s += v;
    s2 += v * v;
  }
  __shared__ float ls[256], ls2[256];
  ls[threadIdx.x] = s;
  ls2[threadIdx.x] = s2;
  __syncthreads();
  if (threadIdx.x < 64) {
    atomicAdd(&stats[j], ls[j] + ls[j + 64] + ls[j + 128] + ls[j + 192]);
    atomicAdd(&stats[64 + j], ls2[j] + ls2[j + 64] + ls2[j + 128] + ls2[j + 192]);
  }
}

// ---------------- GEMM2 standalone (BN+ReLU fused input, dinv-scaled output) ----------------
__global__ __launch_bounds__(256) void k_gemm2(const float* __restrict__ X,
                                               const float* __restrict__ W,
                                               const float* __restrict__ dinv,
                                               const float* __restrict__ stats,
                                               const float* __restrict__ gamma,
                                               const float* __restrict__ beta,
                                               unsigned short* __restrict__ Y,
                                               int n, float inv_n) {
  __shared__ float Ws[64 * 64];
  __shared__ float Xs[64 * 68];
  __shared__ float bn_s[192];
  gemm_tile<64, true, true>(Ws, Xs, bn_s, blockIdx.x, X, W, dinv, stats, gamma, beta,
                            Y, n, inv_n);
}

// ---------------- launch ----------------

extern "C" void kernel_launch(void* const* d_in, const int* in_sizes, int n_in,
                              void* d_out, int out_size, void* d_ws, size_t ws_size,
                              hipStream_t stream) {
  const float* x     = (const float*)d_in[0];
  const int*   ei    = (const int*)d_in[1];
  const float* W1    = (const float*)d_in[2];
  const float* b1    = (const float*)d_in[3];
  const float* W2    = (const float*)d_in[4];
  const float* b2    = (const float*)d_in[5];
  const float* gamma = (const float*)d_in[6];
  const float* beta  = (const float*)d_in[7];
  float* out = (float*)d_out;

  const int N = in_sizes[0] / 128;   // 100000
  const int E = in_sizes[1] / 2;     // 1600000
  const int* src = ei;
  const int* dst = ei + E;

  const size_t Npad = ((size_t)N + 256) & ~(size_t)255;

  // workspace layout
  char* p = (char*)d_ws;
  float* dinv    = (float*)p;               p += Npad * 4;
  int*   cnt     = (int*)p;                 p += Npad * 4;
  int*   row_ptr = (int*)p;                 p += Npad * 4;
  int*   blksum  = (int*)p;                 p += 256 * 4;
  int*   rank    = (int*)p;                 p += (size_t)E * 4;
  int*   col     = (int*)p;                 p += (size_t)E * 4;
  unsigned short* h16 = (unsigned short*)p; p += (size_t)N * 64 * 2;  // bf16 table
  float* agg     = (float*)p;               p += (size_t)N * 64 * 4;
  float* stats   = (float*)p;               p += 128 * 4;

  int nb_n  = (N + 255) / 256;
  int nb_n4 = (N + 3) / 4;
  int nb_t  = (N + 63) / 64;
  int nbE   = (E + 1023) / 1024;                 // 4 edges/thread
  int nbS   = (N * 64 + 2047) / 2048;            // 8 bf16 elems/thread
  int nscan = (N + SCAN_CHUNK - 1) / SCAN_CHUNK;
  float inv_n = 1.0f / (float)N;

  // ---- cnt = 0 ----
  k_zero_int<<<nb_n, 256, 0, stream>>>(cnt, N);

  // ---- fused: degree histogram + rank || GEMM1, parity-interleaved ----
  k_fused_deg_gemm1<<<nbE + nb_t, 256, 0, stream>>>(dst, cnt, rank, E, nbE,
                                                    x, W1, h16, N, nb_t);

  // ---- CSR scan (dinv fused; stats zero fused) ----
  k_scan_local<<<nscan, 256, 0, stream>>>(cnt, row_ptr, blksum, dinv, N);
  k_scan_blk<<<1, 64, 0, stream>>>(blksum, nscan, row_ptr, N, stats);
  k_scan_add<<<nscan, 256, 0, stream>>>(row_ptr, blksum, N);

  // ---- fused: CSR fill || table row-scale, mod-3 interleaved ----
  k_fused_fill_scale<<<nbE + nbS, 256, 0, stream>>>(src, dst, rank, row_ptr, col,
                                                    E, nbE, h16, dinv, N);

  // ---- layer 1 aggregation (one row/wave, pair loads) ----
  k_gather_pair<<<nb_n4, 256, 0, stream>>>(h16, row_ptr, col, dinv, b1, agg, N);

  // ---- BN stats ----
  k_bnstats<<<1024, 256, 0, stream>>>(agg, stats, N);

  // ---- layer 2: BN+ReLU fused GEMM -> scaled bf16 table; pair gather ----
  k_gemm2<<<nb_t, 256, 0, stream>>>(agg, W2, dinv, stats, gamma, beta, h16, N, inv_n);
  k_gather_pair<<<nb_n4, 256, 0, stream>>>(h16, row_ptr, col, dinv, b2, out, N);
}